// Round 7
// baseline (6182.558 us; speedup 1.0000x reference)
//
#include <hip/hip_runtime.h>
#include <hip/hip_bf16.h>
#include <math.h>

#define MUL 8
#define NCOL 144   // 16*(1+3+5)

__device__ __forceinline__ float silu_f(float x) { return x / (1.0f + __expf(-x)); }

// ---------------- Kernel 1: per-node MLP -> Ai[N][8] (f32) ----------------
__global__ void node_mlp_kernel(const int* __restrict__ A,
                                const float* __restrict__ emb_table,
                                const float* __restrict__ w1,
                                const float* __restrict__ b1,
                                const float* __restrict__ w2,
                                const float* __restrict__ b2,
                                float* __restrict__ Ai, int N) {
    __shared__ float s_w1[16 * 64];
    __shared__ float s_w2[64 * MUL];
    __shared__ float s_b1[64];
    __shared__ float s_b2[MUL];
    __shared__ float s_emb[10 * 16];
    for (int i = threadIdx.x; i < 16 * 64; i += blockDim.x) s_w1[i] = w1[i];
    for (int i = threadIdx.x; i < 64 * MUL; i += blockDim.x) s_w2[i] = w2[i];
    for (int i = threadIdx.x; i < 64; i += blockDim.x) s_b1[i] = b1[i];
    for (int i = threadIdx.x; i < MUL; i += blockDim.x) s_b2[i] = b2[i];
    for (int i = threadIdx.x; i < 160; i += blockDim.x) s_emb[i] = emb_table[i];
    __syncthreads();

    int n = blockIdx.x * blockDim.x + threadIdx.x;
    if (n >= N) return;
    int a = A[n];

    float h[64];
    #pragma unroll
    for (int j = 0; j < 64; j++) h[j] = s_b1[j];
    #pragma unroll 1
    for (int k = 0; k < 16; k++) {           // k rolled: only LDS dynamic-indexed
        float ek = s_emb[a * 16 + k];
        #pragma unroll
        for (int j = 0; j < 64; j++) h[j] += ek * s_w1[k * 64 + j];
    }
    #pragma unroll
    for (int j = 0; j < 64; j++) h[j] = silu_f(h[j]);

    #pragma unroll 1
    for (int u = 0; u < MUL; u++) {
        float acc = s_b2[u];
        #pragma unroll
        for (int k = 0; k < 64; k++) acc += h[k] * s_w2[k * MUL + u];
        Ai[n * MUL + u] = acc;
    }
}

// ---------------- Kernel 2: per-edge compute + atomic scatter into d_out (f32) ----------------
__global__ void __launch_bounds__(256) edge_kernel(
        const float* __restrict__ pos, const int* __restrict__ batch,
        const int* __restrict__ esrc, const int* __restrict__ edst,
        const float* __restrict__ shifts, const float* __restrict__ cell,
        const float* __restrict__ fw1, const float* __restrict__ fb1,
        const float* __restrict__ fw2, const float* __restrict__ fb2,
        const float* __restrict__ fw3, const float* __restrict__ fb3,
        const float* __restrict__ tpw,
        const float* __restrict__ Ai,
        float* __restrict__ out, float* __restrict__ deg, int E) {
    __shared__ float s_w1[16 * 64];
    __shared__ float s_w2[64 * 64];
    __shared__ float s_w3[64 * 3];
    __shared__ float s_b1[64];
    __shared__ float s_b2[64];
    __shared__ float s_b3[3];
    __shared__ float s_tpw[3 * 1024];  // paths 0,3,9

    for (int i = threadIdx.x; i < 1024; i += blockDim.x) s_w1[i] = fw1[i];
    for (int i = threadIdx.x; i < 4096; i += blockDim.x) s_w2[i] = fw2[i];
    for (int i = threadIdx.x; i < 64; i += blockDim.x) { s_b1[i] = fb1[i]; s_b2[i] = fb2[i]; }
    for (int i = threadIdx.x; i < 192; i += blockDim.x) {
        int j = i / 3, c = i - 3 * j;
        int cc = (c == 0) ? 0 : ((c == 1) ? 3 : 9);
        s_w3[i] = fw3[j * 15 + cc];
    }
    if (threadIdx.x < 3) {
        int cc = (threadIdx.x == 0) ? 0 : ((threadIdx.x == 1) ? 3 : 9);
        s_b3[threadIdx.x] = fb3[cc];
    }
    for (int i = threadIdx.x; i < 3 * 1024; i += blockDim.x) {
        int l = i >> 10, r = i & 1023;
        int p = (l == 0) ? 0 : ((l == 1) ? 3 : 9);
        s_tpw[i] = tpw[p * 1024 + r];
    }
    __syncthreads();

    int e = blockIdx.x * blockDim.x + threadIdx.x;
    if (e >= E) return;

    int s = esrc[e], d = edst[e];

    // geometry: edge_vec = pos[dst]-pos[src] + shifts[e] @ cell[batch[src]]
    int g = batch[s];
    float sh0 = shifts[e * 3 + 0], sh1 = shifts[e * 3 + 1], sh2 = shifts[e * 3 + 2];
    const float* cg = cell + g * 9;
    float sv0 = sh0 * cg[0] + sh1 * cg[3] + sh2 * cg[6];
    float sv1 = sh0 * cg[1] + sh1 * cg[4] + sh2 * cg[7];
    float sv2 = sh0 * cg[2] + sh1 * cg[5] + sh2 * cg[8];
    float vx = pos[d * 3 + 0] - pos[s * 3 + 0] + sv0;
    float vy = pos[d * 3 + 1] - pos[s * 3 + 1] + sv1;
    float vz = pos[d * 3 + 2] - pos[s * 3 + 2] + sv2;
    float len = sqrtf(vx * vx + vy * vy + vz * vz);
    float inv = 1.0f / fmaxf(len, 1e-8f);
    float nx = vx * inv, ny = vy * inv, nz = vz * inv;

    // radial MLP: 16 gaussians -> 64 -> 64 -> 3 gate columns {0,3,9}
    float r = len * (17.0f / 5.0f);
    float h[64];
    #pragma unroll
    for (int j = 0; j < 64; j++) h[j] = s_b1[j];
    #pragma unroll 1
    for (int k = 0; k < 16; k++) {
        float dk = r - (float)(k + 1);
        float ek = __expf(-dk * dk) * (4.0f / 1.12f);   // * sqrt(NB) / 1.12
        #pragma unroll
        for (int j = 0; j < 64; j++) h[j] += ek * s_w1[k * 64 + j];
    }
    #pragma unroll
    for (int j = 0; j < 64; j++) h[j] = silu_f(h[j]);

    float g0 = s_b3[0], g1 = s_b3[1], g2 = s_b3[2];
    #pragma unroll 2
    for (int j = 0; j < 64; j++) {
        float a = s_b2[j];
        #pragma unroll
        for (int k = 0; k < 64; k++) a += h[k] * s_w2[k * 64 + j];
        a = silu_f(a);
        g0 += a * s_w3[j * 3 + 0];
        g1 += a * s_w3[j * 3 + 1];
        g2 += a * s_w3[j * 3 + 2];
    }
    g0 *= 0.125f; g1 *= 0.125f; g2 *= 0.125f;   // PATH_NORM = 1/sqrt(64)

    // bilinear: t_l[w] = sum_{u,v} Ai[src][u]*Ai[dst][v]*tpw[l][u][v][w]
    float t0[16], t1[16], t2[16];
    #pragma unroll
    for (int w = 0; w < 16; w++) { t0[w] = 0.f; t1[w] = 0.f; t2[w] = 0.f; }
    int s8 = s * MUL, d8 = d * MUL;
    float Ad[8];
    #pragma unroll
    for (int v = 0; v < 8; v++) Ad[v] = Ai[d8 + v];
    #pragma unroll 1
    for (int u = 0; u < 8; u++) {
        float asu = Ai[s8 + u];
        int off = u * 128;
        #pragma unroll
        for (int v = 0; v < 8; v++) {
            float p = asu * Ad[v];
            int o2 = off + v * 16;
            #pragma unroll
            for (int w = 0; w < 16; w++) {
                t0[w] += p * s_tpw[o2 + w];
                t1[w] += p * s_tpw[1024 + o2 + w];
                t2[w] += p * s_tpw[2048 + o2 + w];
            }
        }
    }
    #pragma unroll
    for (int w = 0; w < 16; w++) { t0[w] *= g0; t1[w] *= g1; t2[w] *= g2; }

    // spherical harmonics
    const float s3 = 1.7320508075688772f;
    const float s15 = 3.872983346207417f;
    const float s5h = 1.118033988749895f;   // sqrt(5)/2
    float y1_[3] = { s3 * nx, s3 * ny, s3 * nz };
    float y2_[5] = { s15 * nx * ny, s15 * ny * nz, s5h * (3.f * nz * nz - 1.f),
                     s15 * nx * nz, 0.5f * s15 * (nx * nx - ny * ny) };

    // scatter directly into f32 output accumulator
    float* o = out + (size_t)d * NCOL;
    #pragma unroll
    for (int w = 0; w < 16; w++) atomicAdd(o + w, t0[w]);
    #pragma unroll
    for (int w = 0; w < 16; w++) {
        #pragma unroll
        for (int i = 0; i < 3; i++) atomicAdd(o + 16 + w * 3 + i, t1[w] * y1_[i]);
    }
    #pragma unroll
    for (int w = 0; w < 16; w++) {
        #pragma unroll
        for (int i = 0; i < 5; i++) atomicAdd(o + 64 + w * 5 + i, t2[w] * y2_[i]);
    }
    atomicAdd(deg + d, 1.0f);
}

// ---------------- Kernel 3: divide by degree, in place (f32 out) ----------------
__global__ void finalize_kernel(float* __restrict__ out, const float* __restrict__ deg,
                                int total) {
    int idx = blockIdx.x * blockDim.x + threadIdx.x;
    if (idx >= total) return;
    int n = idx / NCOL;
    float c = fmaxf(deg[n], 1.0f);
    out[idx] = out[idx] / c;
}

extern "C" void kernel_launch(void* const* d_in, const int* in_sizes, int n_in,
                              void* d_out, int out_size, void* d_ws, size_t ws_size,
                              hipStream_t stream) {
    const float* pos    = (const float*)d_in[0];
    const int*   A      = (const int*)d_in[1];
    const int*   batch  = (const int*)d_in[2];
    const int*   esrc   = (const int*)d_in[3];
    const int*   edst   = (const int*)d_in[4];
    const float* shifts = (const float*)d_in[5];
    const float* cellp  = (const float*)d_in[6];
    const float* embt   = (const float*)d_in[7];
    const float* aw1    = (const float*)d_in[8];
    const float* ab1    = (const float*)d_in[9];
    const float* aw2    = (const float*)d_in[10];
    const float* ab2    = (const float*)d_in[11];
    const float* fw1    = (const float*)d_in[12];
    const float* fb1    = (const float*)d_in[13];
    const float* fw2    = (const float*)d_in[14];
    const float* fb2    = (const float*)d_in[15];
    const float* fw3    = (const float*)d_in[16];
    const float* fb3    = (const float*)d_in[17];
    const float* tpw    = (const float*)d_in[18];

    int N = in_sizes[1];
    int E = in_sizes[3];

    float* Ai  = (float*)d_ws;            // N*8 f32
    float* deg = Ai + (size_t)N * MUL;    // N f32
    float* out = (float*)d_out;           // N*144 f32 accumulator + final result

    // d_out is poisoned before timed launches — zero it ourselves.
    hipMemsetAsync(out, 0, (size_t)out_size * sizeof(float), stream);
    hipMemsetAsync(deg, 0, (size_t)N * sizeof(float), stream);

    node_mlp_kernel<<<(N + 255) / 256, 256, 0, stream>>>(A, embt, aw1, ab1, aw2, ab2, Ai, N);

    edge_kernel<<<(E + 255) / 256, 256, 0, stream>>>(pos, batch, esrc, edst, shifts, cellp,
                                                     fw1, fb1, fw2, fb2, fw3, fb3, tpw,
                                                     Ai, out, deg, E);

    int total = N * NCOL;
    finalize_kernel<<<(total + 255) / 256, 256, 0, stream>>>(out, deg, total);
}

// Round 8
// 843.976 us; speedup vs baseline: 7.3255x; 7.3255x over previous
//
#include <hip/hip_runtime.h>
#include <hip/hip_bf16.h>
#include <math.h>

#define MUL 8
#define NCOL 144   // 16*(1+3+5)
#define EREC 56    // per-edge record: t0[16] t1[16] t2[16] y1[3] y2[5]

__device__ __forceinline__ float silu_f(float x) { return x / (1.0f + __expf(-x)); }

// ---------------- node MLP -> Ai[N][8] ----------------
__global__ void node_mlp_kernel(const int* __restrict__ A,
                                const float* __restrict__ emb_table,
                                const float* __restrict__ w1,
                                const float* __restrict__ b1,
                                const float* __restrict__ w2,
                                const float* __restrict__ b2,
                                float* __restrict__ Ai, int N) {
    __shared__ float s_w1[16 * 64];
    __shared__ float s_w2[64 * MUL];
    __shared__ float s_b1[64];
    __shared__ float s_b2[MUL];
    __shared__ float s_emb[10 * 16];
    for (int i = threadIdx.x; i < 16 * 64; i += blockDim.x) s_w1[i] = w1[i];
    for (int i = threadIdx.x; i < 64 * MUL; i += blockDim.x) s_w2[i] = w2[i];
    for (int i = threadIdx.x; i < 64; i += blockDim.x) s_b1[i] = b1[i];
    for (int i = threadIdx.x; i < MUL; i += blockDim.x) s_b2[i] = b2[i];
    for (int i = threadIdx.x; i < 160; i += blockDim.x) s_emb[i] = emb_table[i];
    __syncthreads();

    int n = blockIdx.x * blockDim.x + threadIdx.x;
    if (n >= N) return;
    int a = A[n];

    float h[64];
    #pragma unroll
    for (int j = 0; j < 64; j++) h[j] = s_b1[j];
    #pragma unroll 1
    for (int k = 0; k < 16; k++) {
        float ek = s_emb[a * 16 + k];
        #pragma unroll
        for (int j = 0; j < 64; j++) h[j] += ek * s_w1[k * 64 + j];
    }
    #pragma unroll
    for (int j = 0; j < 64; j++) h[j] = silu_f(h[j]);

    #pragma unroll 1
    for (int u = 0; u < MUL; u++) {
        float acc = s_b2[u];
        #pragma unroll
        for (int k = 0; k < 64; k++) acc += h[k] * s_w2[k * MUL + u];
        Ai[n * MUL + u] = acc;
    }
}

// ---------------- CSR build ----------------
__global__ void count_kernel(const int* __restrict__ edst, int* __restrict__ count, int E) {
    int e = blockIdx.x * blockDim.x + threadIdx.x;
    if (e < E) atomicAdd(&count[edst[e]], 1);
}

// single-block exclusive scan: off[0..N] from count[0..N-1]
__global__ void scan_kernel(const int* __restrict__ count, int* __restrict__ off, int N) {
    __shared__ int sums[1024];
    int L = N + 1;
    int chunk = (L + 1023) / 1024;
    int t = threadIdx.x;
    int lo = t * chunk;
    int hi = lo + chunk; if (hi > L) hi = L;
    int local = 0;
    for (int i = lo; i < hi; i++) local += (i < N) ? count[i] : 0;
    sums[t] = local;
    __syncthreads();
    for (int s = 1; s < 1024; s <<= 1) {
        int v = (t >= s) ? sums[t - s] : 0;
        __syncthreads();
        sums[t] += v;
        __syncthreads();
    }
    int run = (t == 0) ? 0 : sums[t - 1];
    for (int i = lo; i < hi; i++) {
        off[i] = run;
        run += (i < N) ? count[i] : 0;
    }
}

__global__ void fill_kernel(const int* __restrict__ edst, const int* __restrict__ off,
                            int* __restrict__ cursor, int* __restrict__ list, int E) {
    int e = blockIdx.x * blockDim.x + threadIdx.x;
    if (e >= E) return;
    int d = edst[e];
    int p = atomicAdd(&cursor[d], 1);
    list[off[d] + p] = e;
}

// ---------------- phase A: per-edge compute -> 56-float record ----------------
__global__ void __launch_bounds__(256) edge_compute_kernel(
        const float* __restrict__ pos, const int* __restrict__ batch,
        const int* __restrict__ esrc, const int* __restrict__ edst,
        const float* __restrict__ shifts, const float* __restrict__ cell,
        const float* __restrict__ fw1, const float* __restrict__ fb1,
        const float* __restrict__ fw2, const float* __restrict__ fb2,
        const float* __restrict__ fw3, const float* __restrict__ fb3,
        const float* __restrict__ tpw,
        const float* __restrict__ Ai,
        float* __restrict__ ebuf, int E) {
    __shared__ float s_w1[16 * 64];
    __shared__ float s_w2[64 * 64];
    __shared__ float s_w3[64 * 3];
    __shared__ float s_b1[64];
    __shared__ float s_b2[64];
    __shared__ float s_b3[3];
    __shared__ float s_tpw[3 * 1024];

    for (int i = threadIdx.x; i < 1024; i += blockDim.x) s_w1[i] = fw1[i];
    for (int i = threadIdx.x; i < 4096; i += blockDim.x) s_w2[i] = fw2[i];
    for (int i = threadIdx.x; i < 64; i += blockDim.x) { s_b1[i] = fb1[i]; s_b2[i] = fb2[i]; }
    for (int i = threadIdx.x; i < 192; i += blockDim.x) {
        int j = i / 3, c = i - 3 * j;
        int cc = (c == 0) ? 0 : ((c == 1) ? 3 : 9);
        s_w3[i] = fw3[j * 15 + cc];
    }
    if (threadIdx.x < 3) {
        int cc = (threadIdx.x == 0) ? 0 : ((threadIdx.x == 1) ? 3 : 9);
        s_b3[threadIdx.x] = fb3[cc];
    }
    for (int i = threadIdx.x; i < 3 * 1024; i += blockDim.x) {
        int l = i >> 10, r = i & 1023;
        int p = (l == 0) ? 0 : ((l == 1) ? 3 : 9);
        s_tpw[i] = tpw[p * 1024 + r];
    }
    __syncthreads();

    int e = blockIdx.x * blockDim.x + threadIdx.x;
    if (e >= E) return;

    int s = esrc[e], d = edst[e];

    int g = batch[s];
    float sh0 = shifts[e * 3 + 0], sh1 = shifts[e * 3 + 1], sh2 = shifts[e * 3 + 2];
    const float* cg = cell + g * 9;
    float sv0 = sh0 * cg[0] + sh1 * cg[3] + sh2 * cg[6];
    float sv1 = sh0 * cg[1] + sh1 * cg[4] + sh2 * cg[7];
    float sv2 = sh0 * cg[2] + sh1 * cg[5] + sh2 * cg[8];
    float vx = pos[d * 3 + 0] - pos[s * 3 + 0] + sv0;
    float vy = pos[d * 3 + 1] - pos[s * 3 + 1] + sv1;
    float vz = pos[d * 3 + 2] - pos[s * 3 + 2] + sv2;
    float len = sqrtf(vx * vx + vy * vy + vz * vz);
    float inv = 1.0f / fmaxf(len, 1e-8f);
    float nx = vx * inv, ny = vy * inv, nz = vz * inv;

    // radial MLP
    float r = len * (17.0f / 5.0f);
    float h[64];
    #pragma unroll
    for (int j = 0; j < 64; j++) h[j] = s_b1[j];
    #pragma unroll 1
    for (int k = 0; k < 16; k++) {
        float dk = r - (float)(k + 1);
        float ek = __expf(-dk * dk) * (4.0f / 1.12f);
        #pragma unroll
        for (int j = 0; j < 64; j++) h[j] += ek * s_w1[k * 64 + j];
    }
    #pragma unroll
    for (int j = 0; j < 64; j++) h[j] = silu_f(h[j]);

    float g0 = s_b3[0], g1 = s_b3[1], g2 = s_b3[2];
    #pragma unroll 2
    for (int j = 0; j < 64; j++) {
        float a = s_b2[j];
        #pragma unroll
        for (int k = 0; k < 64; k++) a += h[k] * s_w2[k * 64 + j];
        a = silu_f(a);
        g0 += a * s_w3[j * 3 + 0];
        g1 += a * s_w3[j * 3 + 1];
        g2 += a * s_w3[j * 3 + 2];
    }
    g0 *= 0.125f; g1 *= 0.125f; g2 *= 0.125f;

    // outer products (h dead -> registers freed)
    float p[64];
    {
        float As[8], Ad[8];
        int s8 = s * MUL, d8 = d * MUL;
        #pragma unroll
        for (int u = 0; u < 8; u++) { As[u] = Ai[s8 + u]; Ad[u] = Ai[d8 + u]; }
        #pragma unroll
        for (int u = 0; u < 8; u++)
            #pragma unroll
            for (int v = 0; v < 8; v++) p[u * 8 + v] = As[u] * Ad[v];
    }

    float* eb = ebuf + (size_t)e * EREC;
    float4* eb4 = (float4*)eb;

    #pragma unroll 1
    for (int l = 0; l < 3; l++) {
        float gl = (l == 0) ? g0 : ((l == 1) ? g1 : g2);
        const float* W = s_tpw + (l << 10);
        float t[16];
        #pragma unroll
        for (int w = 0; w < 16; w++) t[w] = 0.f;
        #pragma unroll 1
        for (int u = 0; u < 8; u++) {
            #pragma unroll
            for (int v = 0; v < 8; v++) {
                float pv = p[u * 8 + v];
                int o2 = u * 128 + v * 16;
                #pragma unroll
                for (int w = 0; w < 16; w++) t[w] += pv * W[o2 + w];
            }
        }
        #pragma unroll
        for (int w = 0; w < 16; w++) t[w] *= gl;
        eb4[l * 4 + 0] = make_float4(t[0], t[1], t[2], t[3]);
        eb4[l * 4 + 1] = make_float4(t[4], t[5], t[6], t[7]);
        eb4[l * 4 + 2] = make_float4(t[8], t[9], t[10], t[11]);
        eb4[l * 4 + 3] = make_float4(t[12], t[13], t[14], t[15]);
    }

    const float s3 = 1.7320508075688772f;
    const float s15 = 3.872983346207417f;
    const float s5h = 1.118033988749895f;
    float y10 = s3 * nx, y11 = s3 * ny, y12 = s3 * nz;
    float y20 = s15 * nx * ny, y21 = s15 * ny * nz, y22 = s5h * (3.f * nz * nz - 1.f);
    float y23 = s15 * nx * nz, y24 = 0.5f * s15 * (nx * nx - ny * ny);
    eb4[12] = make_float4(y10, y11, y12, y20);
    eb4[13] = make_float4(y21, y22, y23, y24);
}

// ---------------- phase B: gather per node, write out once ----------------
__global__ void __launch_bounds__(192) gather_kernel(
        const float* __restrict__ ebuf, const int* __restrict__ off,
        const int* __restrict__ list, float* __restrict__ out, int N) {
    int n = blockIdx.x;
    int c = threadIdx.x;
    if (c >= NCOL) return;
    int b = off[n], eN = off[n + 1];
    float val = 0.f;
    if (c < 16) {
        for (int j = b; j < eN; j++) {
            size_t base = (size_t)list[j] * EREC;
            val += ebuf[base + c];
        }
    } else if (c < 64) {
        int rr = c - 16, w = rr / 3, i = rr - 3 * w;
        for (int j = b; j < eN; j++) {
            size_t base = (size_t)list[j] * EREC;
            val += ebuf[base + 16 + w] * ebuf[base + 48 + i];
        }
    } else {
        int rr = c - 64, w = rr / 5, i = rr - 5 * w;
        for (int j = b; j < eN; j++) {
            size_t base = (size_t)list[j] * EREC;
            val += ebuf[base + 32 + w] * ebuf[base + 51 + i];
        }
    }
    float dg = (float)(eN - b);
    out[(size_t)n * NCOL + c] = val / fmaxf(dg, 1.0f);
}

// ================= fallback (small ws): R7 atomic path =================
__global__ void __launch_bounds__(256) edge_atomic_kernel(
        const float* __restrict__ pos, const int* __restrict__ batch,
        const int* __restrict__ esrc, const int* __restrict__ edst,
        const float* __restrict__ shifts, const float* __restrict__ cell,
        const float* __restrict__ fw1, const float* __restrict__ fb1,
        const float* __restrict__ fw2, const float* __restrict__ fb2,
        const float* __restrict__ fw3, const float* __restrict__ fb3,
        const float* __restrict__ tpw,
        const float* __restrict__ Ai,
        float* __restrict__ out, float* __restrict__ deg, int E) {
    __shared__ float s_w1[16 * 64];
    __shared__ float s_w2[64 * 64];
    __shared__ float s_w3[64 * 3];
    __shared__ float s_b1[64];
    __shared__ float s_b2[64];
    __shared__ float s_b3[3];
    __shared__ float s_tpw[3 * 1024];
    for (int i = threadIdx.x; i < 1024; i += blockDim.x) s_w1[i] = fw1[i];
    for (int i = threadIdx.x; i < 4096; i += blockDim.x) s_w2[i] = fw2[i];
    for (int i = threadIdx.x; i < 64; i += blockDim.x) { s_b1[i] = fb1[i]; s_b2[i] = fb2[i]; }
    for (int i = threadIdx.x; i < 192; i += blockDim.x) {
        int j = i / 3, c = i - 3 * j;
        int cc = (c == 0) ? 0 : ((c == 1) ? 3 : 9);
        s_w3[i] = fw3[j * 15 + cc];
    }
    if (threadIdx.x < 3) {
        int cc = (threadIdx.x == 0) ? 0 : ((threadIdx.x == 1) ? 3 : 9);
        s_b3[threadIdx.x] = fb3[cc];
    }
    for (int i = threadIdx.x; i < 3 * 1024; i += blockDim.x) {
        int l = i >> 10, r = i & 1023;
        int p = (l == 0) ? 0 : ((l == 1) ? 3 : 9);
        s_tpw[i] = tpw[p * 1024 + r];
    }
    __syncthreads();
    int e = blockIdx.x * blockDim.x + threadIdx.x;
    if (e >= E) return;
    int s = esrc[e], d = edst[e];
    int g = batch[s];
    float sh0 = shifts[e * 3 + 0], sh1 = shifts[e * 3 + 1], sh2 = shifts[e * 3 + 2];
    const float* cg = cell + g * 9;
    float sv0 = sh0 * cg[0] + sh1 * cg[3] + sh2 * cg[6];
    float sv1 = sh0 * cg[1] + sh1 * cg[4] + sh2 * cg[7];
    float sv2 = sh0 * cg[2] + sh1 * cg[5] + sh2 * cg[8];
    float vx = pos[d * 3 + 0] - pos[s * 3 + 0] + sv0;
    float vy = pos[d * 3 + 1] - pos[s * 3 + 1] + sv1;
    float vz = pos[d * 3 + 2] - pos[s * 3 + 2] + sv2;
    float len = sqrtf(vx * vx + vy * vy + vz * vz);
    float inv = 1.0f / fmaxf(len, 1e-8f);
    float nx = vx * inv, ny = vy * inv, nz = vz * inv;
    float r = len * (17.0f / 5.0f);
    float h[64];
    #pragma unroll
    for (int j = 0; j < 64; j++) h[j] = s_b1[j];
    #pragma unroll 1
    for (int k = 0; k < 16; k++) {
        float dk = r - (float)(k + 1);
        float ek = __expf(-dk * dk) * (4.0f / 1.12f);
        #pragma unroll
        for (int j = 0; j < 64; j++) h[j] += ek * s_w1[k * 64 + j];
    }
    #pragma unroll
    for (int j = 0; j < 64; j++) h[j] = silu_f(h[j]);
    float g0 = s_b3[0], g1 = s_b3[1], g2 = s_b3[2];
    #pragma unroll 2
    for (int j = 0; j < 64; j++) {
        float a = s_b2[j];
        #pragma unroll
        for (int k = 0; k < 64; k++) a += h[k] * s_w2[k * 64 + j];
        a = silu_f(a);
        g0 += a * s_w3[j * 3 + 0];
        g1 += a * s_w3[j * 3 + 1];
        g2 += a * s_w3[j * 3 + 2];
    }
    g0 *= 0.125f; g1 *= 0.125f; g2 *= 0.125f;
    float t0[16], t1[16], t2[16];
    #pragma unroll
    for (int w = 0; w < 16; w++) { t0[w] = 0.f; t1[w] = 0.f; t2[w] = 0.f; }
    int s8 = s * MUL, d8 = d * MUL;
    float Ad[8];
    #pragma unroll
    for (int v = 0; v < 8; v++) Ad[v] = Ai[d8 + v];
    #pragma unroll 1
    for (int u = 0; u < 8; u++) {
        float asu = Ai[s8 + u];
        int offp = u * 128;
        #pragma unroll
        for (int v = 0; v < 8; v++) {
            float p = asu * Ad[v];
            int o2 = offp + v * 16;
            #pragma unroll
            for (int w = 0; w < 16; w++) {
                t0[w] += p * s_tpw[o2 + w];
                t1[w] += p * s_tpw[1024 + o2 + w];
                t2[w] += p * s_tpw[2048 + o2 + w];
            }
        }
    }
    #pragma unroll
    for (int w = 0; w < 16; w++) { t0[w] *= g0; t1[w] *= g1; t2[w] *= g2; }
    const float s3 = 1.7320508075688772f;
    const float s15 = 3.872983346207417f;
    const float s5h = 1.118033988749895f;
    float y1_[3] = { s3 * nx, s3 * ny, s3 * nz };
    float y2_[5] = { s15 * nx * ny, s15 * ny * nz, s5h * (3.f * nz * nz - 1.f),
                     s15 * nx * nz, 0.5f * s15 * (nx * nx - ny * ny) };
    float* o = out + (size_t)d * NCOL;
    #pragma unroll
    for (int w = 0; w < 16; w++) atomicAdd(o + w, t0[w]);
    #pragma unroll
    for (int w = 0; w < 16; w++)
        #pragma unroll
        for (int i = 0; i < 3; i++) atomicAdd(o + 16 + w * 3 + i, t1[w] * y1_[i]);
    #pragma unroll
    for (int w = 0; w < 16; w++)
        #pragma unroll
        for (int i = 0; i < 5; i++) atomicAdd(o + 64 + w * 5 + i, t2[w] * y2_[i]);
    atomicAdd(deg + d, 1.0f);
}

__global__ void finalize_kernel(float* __restrict__ out, const float* __restrict__ deg, int total) {
    int idx = blockIdx.x * blockDim.x + threadIdx.x;
    if (idx >= total) return;
    int n = idx / NCOL;
    out[idx] = out[idx] / fmaxf(deg[n], 1.0f);
}

extern "C" void kernel_launch(void* const* d_in, const int* in_sizes, int n_in,
                              void* d_out, int out_size, void* d_ws, size_t ws_size,
                              hipStream_t stream) {
    const float* pos    = (const float*)d_in[0];
    const int*   A      = (const int*)d_in[1];
    const int*   batch  = (const int*)d_in[2];
    const int*   esrc   = (const int*)d_in[3];
    const int*   edst   = (const int*)d_in[4];
    const float* shifts = (const float*)d_in[5];
    const float* cellp  = (const float*)d_in[6];
    const float* embt   = (const float*)d_in[7];
    const float* aw1    = (const float*)d_in[8];
    const float* ab1    = (const float*)d_in[9];
    const float* aw2    = (const float*)d_in[10];
    const float* ab2    = (const float*)d_in[11];
    const float* fw1    = (const float*)d_in[12];
    const float* fb1    = (const float*)d_in[13];
    const float* fw2    = (const float*)d_in[14];
    const float* fb2    = (const float*)d_in[15];
    const float* fw3    = (const float*)d_in[16];
    const float* fb3    = (const float*)d_in[17];
    const float* tpw    = (const float*)d_in[18];

    int N = in_sizes[1];
    int E = in_sizes[3];
    float* out = (float*)d_out;

    // ws layout (CSR path): Ai[N*8] | count[N] | cursor[N] | off[N+1] | list[E] | ebuf[E*56]
    size_t need = (size_t)N * 32 + (size_t)N * 4 * 2 + (size_t)(N + 1) * 4
                + (size_t)E * 4 + (size_t)E * EREC * 4 + 256;

    if (ws_size >= need) {
        float* Ai    = (float*)d_ws;
        int*   count = (int*)(Ai + (size_t)N * MUL);
        int*   cursor= count + N;
        int*   off   = cursor + N;
        int*   list  = off + (N + 1);
        float* ebuf  = (float*)(list + E);

        hipMemsetAsync(count, 0, (size_t)N * 2 * sizeof(int), stream);  // count + cursor

        node_mlp_kernel<<<(N + 255) / 256, 256, 0, stream>>>(A, embt, aw1, ab1, aw2, ab2, Ai, N);
        count_kernel<<<(E + 255) / 256, 256, 0, stream>>>(edst, count, E);
        scan_kernel<<<1, 1024, 0, stream>>>(count, off, N);
        fill_kernel<<<(E + 255) / 256, 256, 0, stream>>>(edst, off, cursor, list, E);

        edge_compute_kernel<<<(E + 255) / 256, 256, 0, stream>>>(
            pos, batch, esrc, edst, shifts, cellp,
            fw1, fb1, fw2, fb2, fw3, fb3, tpw, Ai, ebuf, E);

        gather_kernel<<<N, 192, 0, stream>>>(ebuf, off, list, out, N);
    } else {
        // fallback: atomic scatter (slow but ws-light)
        float* Ai  = (float*)d_ws;
        float* deg = Ai + (size_t)N * MUL;
        hipMemsetAsync(out, 0, (size_t)out_size * sizeof(float), stream);
        hipMemsetAsync(deg, 0, (size_t)N * sizeof(float), stream);
        node_mlp_kernel<<<(N + 255) / 256, 256, 0, stream>>>(A, embt, aw1, ab1, aw2, ab2, Ai, N);
        edge_atomic_kernel<<<(E + 255) / 256, 256, 0, stream>>>(
            pos, batch, esrc, edst, shifts, cellp,
            fw1, fb1, fw2, fb2, fw3, fb3, tpw, Ai, out, deg, E);
        int total = N * NCOL;
        finalize_kernel<<<(total + 255) / 256, 256, 0, stream>>>(out, deg, total);
    }
}